// Round 16
// baseline (275.832 us; speedup 1.0000x reference)
//
#include <hip/hip_runtime.h>
#include <hip/hip_bf16.h>
#include <cmath>

// B=32, T=512, D=256, H=8, HD=32, L=2, W=10, NTOK=16384

using short8 = __attribute__((ext_vector_type(8))) short;
using short4v = __attribute__((ext_vector_type(4))) short;
using f32x4  = __attribute__((ext_vector_type(4))) float;

__device__ inline float gelu_f(float x) {
    return 0.5f * x * (1.0f + erff(x * 0.70710678118654752f));
}

__device__ inline short f2bf(float x) {
    union { float f; unsigned u; } v; v.f = x;
    return (short)((v.u + 0x7fffu + ((v.u >> 16) & 1u)) >> 16);
}

__device__ inline float bf2f(short v) {
    union { unsigned u; float f; } x; x.u = ((unsigned)(unsigned short)v) << 16;
    return x.f;
}

__device__ inline unsigned packbf(float lo, float hi) {
    union { float f; unsigned u; } a, b; a.f = lo; b.f = hi;
    unsigned ra = (a.u + 0x7fffu + ((a.u >> 16) & 1u)) >> 16;
    unsigned rb = (b.u + 0x7fffu + ((b.u >> 16) & 1u)) >> 16;
    return (rb << 16) | (ra & 0xffffu);
}

#define GLOAD16(gp, lp) __builtin_amdgcn_global_load_lds( \
    (const __attribute__((address_space(1))) void*)(gp), \
    (__attribute__((address_space(3))) void*)(lp), 16, 0, 0)

// ---------------------------------------------------------------------------
// prep: [0,436) weight transpose (4 tiles/block); [436,468) stats+MLP.
__global__ __launch_bounds__(256) void prep(
    const float* __restrict__ fusion_w, const float* __restrict__ in_proj_w,
    const float* __restrict__ out_proj_w, const float* __restrict__ ff1_w,
    const float* __restrict__ ff2_w, const float* __restrict__ cw1,
    short* __restrict__ wts,
    const int* __restrict__ s,
    short* __restrict__ semb,
    const float* __restrict__ sw1, const float* __restrict__ sb1,
    const float* __restrict__ sw2, const float* __restrict__ sb2)
{
    __shared__ float tile[4][32][33];
    __shared__ float sv_sh[512];
    __shared__ float m_sh[512];
    __shared__ float sw2_sh[2048];

    if (blockIdx.x < 436) {
        const int b0[10]      = {0,128,320,512,576,640,896,1152,1408,1664};
        const int Ks[10]      = {512,256,256,256,256,256,256,1024,1024,320};
        const int Ns[10]      = {256,768,768,256,256,1024,1024,256,256,256};
        const int sidx[10]    = {0,1,1,2,2,3,3,4,4,5};
        const size_t soff[10] = {0,0,196608,0,65536,0,262144,0,262144,0};
        const size_t doff[10] = {0,131072,327680,524288,589824,655360,917504,1179648,1441792,1703936};
        const float* srcs[6] = {fusion_w, in_proj_w, out_proj_w, ff1_w, ff2_w, cw1};
        const int c = threadIdx.x & 31, r = threadIdx.x >> 5;

        int mis[4], txs[4], tys[4];
#pragma unroll
        for (int i = 0; i < 4; ++i) {
            int tg = blockIdx.x * 4 + i;
            int mi = 0;
            while (mi < 9 && tg >= b0[mi + 1]) ++mi;
            int bl = tg - b0[mi];
            mis[i] = mi;
            txs[i] = bl % (Ns[mi] >> 5);
            tys[i] = bl / (Ns[mi] >> 5);
        }
#pragma unroll
        for (int i = 0; i < 4; ++i) {
            const float* src = srcs[sidx[mis[i]]] + soff[mis[i]];
            const int N = Ns[mis[i]];
#pragma unroll
            for (int u = 0; u < 4; ++u)
                tile[i][r + u * 8][c] =
                    src[(size_t)(tys[i] * 32 + r + u * 8) * N + txs[i] * 32 + c];
        }
        __syncthreads();
#pragma unroll
        for (int i = 0; i < 4; ++i) {
            short* dst = wts + doff[mis[i]];
            const int K = Ks[mis[i]];
#pragma unroll
            for (int u = 0; u < 4; ++u)
                dst[(size_t)(txs[i] * 32 + r + u * 8) * K + tys[i] * 32 + c] =
                    f2bf(tile[i][c][r + u * 8]);
        }
    } else {
        const int b = blockIdx.x - 436;
        const int tt = threadIdx.x;
        for (int t = tt; t < 512; t += 256) {
            int sval = s[b * 512 + t];
            bool mk = sval >= 0;
            sv_sh[t] = mk ? (float)sval : 0.f;
            m_sh[t] = mk ? 1.f : 0.f;
        }
        for (int i = tt; i < 2048; i += 256) sw2_sh[i] = sw2[i];
        __syncthreads();
        for (int half = 0; half < 2; ++half) {
            const int t = tt + half * 256;
            float mf10 = 0, sf10 = 0, mf5 = 0, sf5 = 0, d9 = 0;
#pragma unroll
            for (int k = 0; k < 10; ++k) {
                int idx = t - k;
                if (idx >= 0) {
                    float mv = m_sh[idx], sv = sv_sh[idx];
                    mf10 += mv; sf10 += sv;
                    if (k < 5) { mf5 += mv; sf5 += sv; }
                    if (k < 9 && idx >= 1) {
                        if (sv != sv_sh[idx - 1] && mv > 0.5f && m_sh[idx - 1] > 0.5f) d9 += 1.f;
                    }
                }
            }
            float run, mx;
            {
                int x0 = t - 9;
                run = (x0 >= 0) ? m_sh[x0] : 0.f;
                mx = run;
#pragma unroll
                for (int j = 1; j < 10; ++j) {
                    int xc = t + j - 9, xp = xc - 1;
                    float sc = (xc >= 0) ? sv_sh[xc] : 0.f;
                    float sp = (xp >= 0) ? sv_sh[xp] : 0.f;
                    float mc = (xc >= 0) ? m_sh[xc] : 0.f;
                    float mp = (xp >= 0) ? m_sh[xp] : 0.f;
                    bool eq = (sc == sp) && (mp > 0.5f);
                    run = (mc > 0.5f) ? ((eq ? run : 0.f) + 1.f) : 0.f;
                    mx = fmaxf(mx, run);
                }
            }
            float f[6];
            f[0] = sf10 / (mf10 + 1e-6f);
            f[1] = sf5 / (mf5 + 1e-6f);
            f[2] = d9 / (mf10 + 1e-6f);
            f[3] = mx * 0.1f;
            f[4] = (float)t * (1.f / 512.f);
            f[5] = mf10 * 0.1f;

            float hid[32];
#pragma unroll
            for (int j2 = 0; j2 < 32; ++j2) {
                float a = sb1[j2];
#pragma unroll
                for (int i = 0; i < 6; ++i) a = fmaf(f[i], sw1[i * 32 + j2], a);
                hid[j2] = fmaxf(a, 0.f);
            }
            short* orow = semb + ((size_t)b * 512 + t) * 64;
            for (int c = 0; c < 64; c += 4) {
                float v0 = sb2[c], v1 = sb2[c + 1], v2 = sb2[c + 2], v3 = sb2[c + 3];
#pragma unroll
                for (int j2 = 0; j2 < 32; ++j2) {
                    float hh = hid[j2];
                    v0 = fmaf(hh, sw2_sh[j2 * 64 + c], v0);
                    v1 = fmaf(hh, sw2_sh[j2 * 64 + c + 1], v1);
                    v2 = fmaf(hh, sw2_sh[j2 * 64 + c + 2], v2);
                    v3 = fmaf(hh, sw2_sh[j2 * 64 + c + 3], v3);
                }
                short4v o; o[0] = f2bf(v0); o[1] = f2bf(v1); o[2] = f2bf(v2); o[3] = f2bf(v3);
                *(short4v*)(orow + c) = o;
            }
        }
    }
}

// ---------------------------------------------------------------------------
// Chunked B-stationary GEMM (round-13 champion).
template<int EPI, int KTOT>
__global__ __launch_bounds__(512) void kbs(
    const short* __restrict__ A, const short* __restrict__ Wt,
    const float* __restrict__ bias,
    short* __restrict__ o0, short* __restrict__ o1, short* __restrict__ o2,
    const float* __restrict__ pos,
    const int* __restrict__ qi, const int* __restrict__ si,
    const float* __restrict__ qe, const float* __restrict__ se)
{
    constexpr int BN = 64;
    constexpr int NCH = (KTOT + 255) / 256;
    __shared__ short Bs[BN * 256];                 // 32 KB
    const int tid = threadIdx.x, lane = tid & 63, wv = tid >> 6;
    const int lg = lane >> 4, lr = lane & 15;
    const int n0 = blockIdx.y * BN;
    const int row0 = blockIdx.x * 128 + wv * 16;

    f32x4 acc[4] = {};
    short8 af[8];

#pragma unroll
    for (int c = 0; c < NCH; ++c) {
        const int ck = (KTOT - c * 256 >= 256) ? 256 : (KTOT - c * 256);
        const int spr = ck >> 3;
        if (c) __syncthreads();
        for (int i = 0; i < (BN * ck) / 8; i += 512) {
            int slot = i + tid;
            int n = slot / spr, posn = slot % spr;
            int g = posn ^ (n & 7);
            GLOAD16(Wt + (size_t)(n0 + n) * KTOT + c * 256 + g * 8, &Bs[slot * 8]);
        }
        const int nkk = ck >> 5;
        if constexpr (EPI == 0) {
            int row = row0 + lr;
            int sv = si[row];
            bool mk = sv >= 0;
            const float* base = (c == 0) ? qe + (size_t)(mk ? qi[row] : 0) * 256
                                         : se + (size_t)(mk ? sv : 0) * 256;
#pragma unroll
            for (int kk = 0; kk < 8; ++kk) {
                const float* p = base + kk * 32 + lg * 8;
                float4 v0 = *(const float4*)p;
                float4 v1 = *(const float4*)(p + 4);
                short8 o;
                o[0] = f2bf(v0.x); o[1] = f2bf(v0.y); o[2] = f2bf(v0.z); o[3] = f2bf(v0.w);
                o[4] = f2bf(v1.x); o[5] = f2bf(v1.y); o[6] = f2bf(v1.z); o[7] = f2bf(v1.w);
                af[kk] = o;
            }
        } else {
            const short* ar = A + (size_t)(row0 + lr) * KTOT + c * 256 + lg * 8;
#pragma unroll
            for (int kk = 0; kk < 8; ++kk)
                if (kk < nkk) af[kk] = *(const short8*)(ar + kk * 32);
        }
        __syncthreads();
#pragma unroll
        for (int kk = 0; kk < 8; ++kk) {
            if (kk >= nkk) break;
#pragma unroll
            for (int j = 0; j < 4; ++j) {
                int n = j * 16 + lr;
                short8 b = *(const short8*)&Bs[n * ck + (((kk * 4 + lg) ^ (n & 7)) << 3)];
                acc[j] = __builtin_amdgcn_mfma_f32_16x16x32_bf16(af[kk], b, acc[j], 0, 0, 0);
            }
        }
    }

    if constexpr (EPI == 0) {
#pragma unroll
        for (int j = 0; j < 4; ++j)
#pragma unroll
        for (int r = 0; r < 4; ++r) {
            int row = row0 + lg * 4 + r;
            int col = n0 + j * 16 + lr;
            float x = acc[j][r] + bias[col];
            x = fmaxf(x, 0.f) + pos[(size_t)(row & 511) * 256 + col];
            o0[(size_t)row * 256 + col] = f2bf(x);
        }
    } else if constexpr (EPI == 1) {
#pragma unroll
        for (int j = 0; j < 4; ++j)
#pragma unroll
        for (int r = 0; r < 4; ++r) {
            int row = row0 + lg * 4 + r;
            int gcol = n0 + j * 16 + lr;
            int t = row & 511, bg = row >> 9;
            int sec = gcol >> 8, cc = gcol & 255;
            int h = cc >> 5, d = cc & 31, bh = bg * 8 + h;
            short v = f2bf(acc[j][r] + bias[gcol]);
            if (sec == 0)      o0[((size_t)bh * 512 + t) * 32 + d] = v;
            else if (sec == 1) o1[((size_t)bh * 512 + t) * 32 + d] = v;
            else {
                int kl = t & 31;
                o2[(size_t)bh * 16384 + (size_t)(t >> 5) * 1024 +
                   (size_t)((kl >> 2) & 3) * 256 + d * 8 + (((kl & 3) << 1) | ((kl >> 4) & 1))] = v;
            }
        }
    } else {  // EPI 2: ff1 gelu
#pragma unroll
        for (int j = 0; j < 4; ++j)
#pragma unroll
        for (int r = 0; r < 4; ++r) {
            int row = row0 + lg * 4 + r;
            int gcol = n0 + j * 16 + lr;
            float x = acc[j][r] + bias[gcol];
            o0[(size_t)row * 1024 + gcol] = f2bf(gelu_f(x));
        }
    }
}

// ---------------------------------------------------------------------------
// Full-row B-stationary GEMM (round-13 champion): BN=256, 32 rows/block,
// K chunks of 128 in 64 KB LDS, grid 512. Fused row-wide epilogues:
// EPI 0: ln; EPI 1: clf.
template<int EPI, int KTOT>
__global__ __launch_bounds__(512) void kfull(
    const short* __restrict__ A, const short* __restrict__ A2,
    const short* __restrict__ Wt, const float* __restrict__ bias,
    short* __restrict__ hb,
    const float* __restrict__ gamma, const float* __restrict__ beta,
    const float* __restrict__ cw2v, const float* __restrict__ cb2,
    const int* __restrict__ smask, float* __restrict__ outlog)
{
    constexpr int NCH = (KTOT + 127) / 128;
    constexpr int KA = (EPI == 1) ? 256 : KTOT;
    __shared__ short Bs[256 * 128];                // 64 KB
    __shared__ float redS[32][4];
    __shared__ float redQ[32][4];
    const int tid = threadIdx.x, lane = tid & 63, wv = tid >> 6;
    const int lg = lane >> 4, lr = lane & 15;
    const int wr = wv >> 2, wc = wv & 3;
    const int row0 = blockIdx.x * 32 + wr * 16;

    f32x4 acc[4] = {};
    short8 af[4];

#pragma unroll
    for (int c = 0; c < NCH; ++c) {
        const int ck = (KTOT - c * 128 >= 128) ? 128 : (KTOT - c * 128);
        const int spr = ck >> 3;
        if (c) __syncthreads();
        for (int i = 0; i < (256 * ck) / 8; i += 512) {
            int slot = i + tid;
            int n = slot / spr, posn = slot % spr;
            int g = posn ^ (n & 7);
            GLOAD16(Wt + (size_t)n * KTOT + c * 128 + g * 8, &Bs[slot * 8]);
        }
        const int nkk = ck >> 5;
        if (EPI == 1 && c == 2) {
            const short* ar2 = A2 + (size_t)(row0 + lr) * 64 + lg * 8;
            af[0] = *(const short8*)(ar2);
            af[1] = *(const short8*)(ar2 + 32);
        } else {
            const short* ar = A + (size_t)(row0 + lr) * KA + c * 128 + lg * 8;
#pragma unroll
            for (int kk = 0; kk < 4; ++kk)
                if (kk < nkk) af[kk] = *(const short8*)(ar + kk * 32);
        }
        __syncthreads();
#pragma unroll
        for (int kk = 0; kk < 4; ++kk) {
            if (kk >= nkk) break;
#pragma unroll
            for (int j = 0; j < 4; ++j) {
                int n = wc * 64 + j * 16 + lr;
                short8 b = *(const short8*)&Bs[n * ck + (((kk * 4 + lg) ^ (n & 7)) << 3)];
                acc[j] = __builtin_amdgcn_mfma_f32_16x16x32_bf16(af[kk], b, acc[j], 0, 0, 0);
            }
        }
    }

    if constexpr (EPI == 0) {
        float ps[4] = {0.f, 0.f, 0.f, 0.f}, pq[4] = {0.f, 0.f, 0.f, 0.f};
#pragma unroll
        for (int j = 0; j < 4; ++j)
#pragma unroll
        for (int r = 0; r < 4; ++r) {
            int row = row0 + lg * 4 + r;
            int col = wc * 64 + j * 16 + lr;
            float x = acc[j][r] + bias[col] + bf2f(hb[(size_t)row * 256 + col]);
            acc[j][r] = x;
            ps[r] += x; pq[r] += x * x;
        }
#pragma unroll
        for (int off = 1; off < 16; off <<= 1)
#pragma unroll
            for (int r = 0; r < 4; ++r) {
                ps[r] += __shfl_xor(ps[r], off);
                pq[r] += __shfl_xor(pq[r], off);
            }
        if (lr == 0) {
#pragma unroll
            for (int r = 0; r < 4; ++r) {
                int rl = wr * 16 + lg * 4 + r;
                redS[rl][wc] = ps[r]; redQ[rl][wc] = pq[r];
            }
        }
        __syncthreads();
#pragma unroll
        for (int r = 0; r < 4; ++r) {
            int rl = wr * 16 + lg * 4 + r;
            int row = row0 + lg * 4 + r;
            float sm = redS[rl][0] + redS[rl][1] + redS[rl][2] + redS[rl][3];
            float sq = redQ[rl][0] + redQ[rl][1] + redQ[rl][2] + redQ[rl][3];
            float mu = sm * (1.f / 256.f);
            float var = sq * (1.f / 256.f) - mu * mu;
            float rstd = rsqrtf(var + 1e-5f);
#pragma unroll
            for (int j = 0; j < 4; ++j) {
                int col = wc * 64 + j * 16 + lr;
                float y = (acc[j][r] - mu) * rstd * gamma[col] + beta[col];
                hb[(size_t)row * 256 + col] = f2bf(y);
            }
        }
    } else {  // EPI 1: classifier
        float p[4] = {0.f, 0.f, 0.f, 0.f};
#pragma unroll
        for (int j = 0; j < 4; ++j)
#pragma unroll
        for (int r = 0; r < 4; ++r) {
            int col = wc * 64 + j * 16 + lr;
            float v = fmaxf(acc[j][r] + bias[col], 0.f);
            p[r] += v * cw2v[col];
        }
#pragma unroll
        for (int off = 1; off < 16; off <<= 1)
#pragma unroll
            for (int r = 0; r < 4; ++r) p[r] += __shfl_xor(p[r], off);
        if (lr == 0) {
#pragma unroll
            for (int r = 0; r < 4; ++r)
                redS[wr * 16 + lg * 4 + r][wc] = p[r];
        }
        __syncthreads();
        if (tid < 32) {
            int row = blockIdx.x * 32 + tid;
            float v = redS[tid][0] + redS[tid][1] + redS[tid][2] + redS[tid][3] + cb2[0];
            outlog[row] = (smask[row] >= 0) ? v : -1e9f;
        }
    }
}

// ---------------------------------------------------------------------------
// MFMA flash attention, fixed-max softmax. 2048 blocks = bh(256) x part(8);
// 4 waves/block, ONE 16-query tile per wave (slot = part*4+wv) -> 2x TLP vs
// paired version. bh = idx & 255 keeps all parts of a bh on one XCD (K/V
// L2-local).
__global__ __launch_bounds__(256) void attn_mfma(
    const short* __restrict__ Qg, const short* __restrict__ Kg,
    const short* __restrict__ VTg, short* __restrict__ O)
{
    __shared__ unsigned Wp[4][16][20];
    const int bh = blockIdx.x & 255, part = blockIdx.x >> 8;
    const int b = bh >> 3, h = bh & 7;
    const int wv = threadIdx.x >> 6, lane = threadIdx.x & 63;
    const int lg = lane >> 4, lr = lane & 15;
    const int slot = part * 4 + wv;
    const short* Qbh = Qg + (size_t)bh * 16384;
    const short* Kbh = Kg + (size_t)bh * 16384;
    const short* Vbh = VTg + (size_t)bh * 16384;
    const float scale = 0.17677669529663687f;

    const int q0 = slot << 4;
    const int nfull = slot >> 1;
    short8 qa = *(const short8*)(Qbh + (size_t)(q0 + lr) * 32 + lg * 8);
    f32x4 o0 = {}, o1 = {};
    float l_[4] = {0.f, 0.f, 0.f, 0.f};

    for (int c = 0; c <= nfull; ++c) {
        int kc = c << 5;
        short8 kf0 = *(const short8*)(Kbh + (size_t)(kc + lr) * 32 + lg * 8);
        short8 kf1 = *(const short8*)(Kbh + (size_t)(kc + 16 + lr) * 32 + lg * 8);
        f32x4 s0 = {}, s1 = {};
        s0 = __builtin_amdgcn_mfma_f32_16x16x32_bf16(qa, kf0, s0, 0, 0, 0);
        s1 = __builtin_amdgcn_mfma_f32_16x16x32_bf16(qa, kf1, s1, 0, 0, 0);
        float p0[4], p1[4];
        if (c < nfull) {
#pragma unroll
            for (int r = 0; r < 4; ++r) {
                p0[r] = __expf(s0[r] * scale);
                p1[r] = __expf(s1[r] * scale);
            }
        } else {
#pragma unroll
            for (int r = 0; r < 4; ++r) {
                int qq = q0 + lg * 4 + r;
                p0[r] = (kc + lr)      > qq ? 0.f : __expf(s0[r] * scale);
                p1[r] = (kc + 16 + lr) > qq ? 0.f : __expf(s1[r] * scale);
            }
        }
#pragma unroll
        for (int r = 0; r < 4; ++r) {
            l_[r] += p0[r] + p1[r];
            Wp[wv][lg * 4 + r][lr] = packbf(p0[r], p1[r]);
        }
        short8 pa = *(const short8*)&Wp[wv][lr][lg * 4];
        short8 vf0 = *(const short8*)(Vbh + (size_t)c * 1024 + lg * 256 + lr * 8);
        short8 vf1 = *(const short8*)(Vbh + (size_t)c * 1024 + lg * 256 + (lr + 16) * 8);
        o0 = __builtin_amdgcn_mfma_f32_16x16x32_bf16(pa, vf0, o0, 0, 0, 0);
        o1 = __builtin_amdgcn_mfma_f32_16x16x32_bf16(pa, vf1, o1, 0, 0, 0);
    }

#pragma unroll
    for (int off = 1; off < 16; off <<= 1)
#pragma unroll
        for (int r = 0; r < 4; ++r) l_[r] += __shfl_xor(l_[r], off);
#pragma unroll
    for (int r = 0; r < 4; ++r) {
        float inv = 1.f / l_[r];
        size_t ro = ((size_t)b * 512 + q0 + lg * 4 + r) * 256 + h * 32;
        O[ro + lr] = f2bf(o0[r] * inv);
        O[ro + 16 + lr] = f2bf(o1[r] * inv);
    }
}

// ---------------------------------------------------------------------------
extern "C" void kernel_launch(void* const* d_in, const int* in_sizes, int n_in,
                              void* d_out, int out_size, void* d_ws, size_t ws_size,
                              hipStream_t stream) {
    const int*   q         = (const int*)d_in[0];
    const int*   s         = (const int*)d_in[1];
    const float* q_embed   = (const float*)d_in[2];
    const float* s_embed   = (const float*)d_in[3];
    const float* pos_embed = (const float*)d_in[4];
    const float* fusion_w  = (const float*)d_in[5];
    const float* fusion_b  = (const float*)d_in[6];
    const float* in_proj_w = (const float*)d_in[7];
    const float* in_proj_b = (const float*)d_in[8];
    const float* out_proj_w= (const float*)d_in[9];
    const float* out_proj_b= (const float*)d_in[10];
    const float* ln1_g     = (const float*)d_in[11];
    const float* ln1_b     = (const float*)d_in[12];
    const float* ln2_g     = (const float*)d_in[13];
    const float* ln2_b     = (const float*)d_in[14];
    const float* ff1_w     = (const float*)d_in[15];
    const float* ff1_b     = (const float*)d_in[16];
    const float* ff2_w     = (const float*)d_in[17];
    const float* ff2_b     = (const float*)d_in[18];
    const float* sw1       = (const float*)d_in[19];
    const float* sb1       = (const float*)d_in[20];
    const float* sw2       = (const float*)d_in[21];
    const float* sb2       = (const float*)d_in[22];
    const float* cw1       = (const float*)d_in[23];
    const float* cb1       = (const float*)d_in[24];
    const float* cw2       = (const float*)d_in[25];
    const float* cb2       = (const float*)d_in[26];
    float* out = (float*)d_out;

    char* base = (char*)d_ws;
    short* hb   = (short*)(base);                     // 8.39 MB
    short* bufA = (short*)(base + 8388608);           // 33.55 MB (ff mid)
    short* att  = (short*)(base + 41943040);          // 8.39 MB
    short* Qg   = (short*)(base + 50331648);          // 8.39 MB
    short* Kg   = (short*)(base + 58720256);          // 8.39 MB
    short* VTg  = (short*)(base + 67108864);          // 8.39 MB
    short* semb = (short*)(base + 75497472);          // 2.10 MB
    short* wts  = (short*)(base + 77594624);          // 3.57 MB

    const size_t W_FUSION = 0, W_INPROJ0 = 131072, W_INPROJ1 = 327680;
    const size_t W_OUTPROJ0 = 524288, W_OUTPROJ1 = 589824;
    const size_t W_FF1_0 = 655360, W_FF1_1 = 917504;
    const size_t W_FF2_0 = 1179648, W_FF2_1 = 1441792;
    const size_t W_CW1 = 1703936;

    prep<<<468, 256, 0, stream>>>(fusion_w, in_proj_w, out_proj_w,
                                  ff1_w, ff2_w, cw1, wts,
                                  s, semb, sw1, sb1, sw2, sb2);
    kbs<0, 512><<<dim3(128, 4), 512, 0, stream>>>(nullptr,
        wts + W_FUSION, fusion_b, hb, nullptr, nullptr,
        pos_embed, q, s, q_embed, s_embed);
    for (int l = 0; l < 2; ++l) {
        kbs<1, 256><<<dim3(128, 12), 512, 0, stream>>>(hb,
            wts + (l ? W_INPROJ1 : W_INPROJ0), in_proj_b + l * 768,
            Qg, Kg, VTg, nullptr, nullptr, nullptr, nullptr, nullptr);
        attn_mfma<<<2048, 256, 0, stream>>>(Qg, Kg, VTg, att);
        kfull<0, 256><<<512, 512, 0, stream>>>(att, nullptr,
            wts + (l ? W_OUTPROJ1 : W_OUTPROJ0), out_proj_b + l * 256,
            hb, ln1_g + l * 256, ln1_b + l * 256,
            nullptr, nullptr, nullptr, nullptr);
        kbs<2, 256><<<dim3(128, 16), 512, 0, stream>>>(hb,
            wts + (l ? W_FF1_1 : W_FF1_0), ff1_b + l * 1024,
            bufA, nullptr, nullptr, nullptr, nullptr, nullptr, nullptr, nullptr);
        kfull<0, 1024><<<512, 512, 0, stream>>>(bufA, nullptr,
            wts + (l ? W_FF2_1 : W_FF2_0), ff2_b + l * 256,
            hb, ln2_g + l * 256, ln2_b + l * 256,
            nullptr, nullptr, nullptr, nullptr);
    }
    kfull<1, 320><<<512, 512, 0, stream>>>(hb, semb,
        wts + W_CW1, cb1, nullptr, nullptr, nullptr,
        cw2, cb2, s, out);
}

// Round 17
// 271.680 us; speedup vs baseline: 1.0153x; 1.0153x over previous
//
#include <hip/hip_runtime.h>
#include <hip/hip_bf16.h>
#include <cmath>

// B=32, T=512, D=256, H=8, HD=32, L=2, W=10, NTOK=16384

using short8 = __attribute__((ext_vector_type(8))) short;
using short4v = __attribute__((ext_vector_type(4))) short;
using f32x4  = __attribute__((ext_vector_type(4))) float;

__device__ inline float gelu_f(float x) {
    return 0.5f * x * (1.0f + erff(x * 0.70710678118654752f));
}

__device__ inline short f2bf(float x) {
    union { float f; unsigned u; } v; v.f = x;
    return (short)((v.u + 0x7fffu + ((v.u >> 16) & 1u)) >> 16);
}

__device__ inline float bf2f(short v) {
    union { unsigned u; float f; } x; x.u = ((unsigned)(unsigned short)v) << 16;
    return x.f;
}

__device__ inline unsigned packbf(float lo, float hi) {
    union { float f; unsigned u; } a, b; a.f = lo; b.f = hi;
    unsigned ra = (a.u + 0x7fffu + ((a.u >> 16) & 1u)) >> 16;
    unsigned rb = (b.u + 0x7fffu + ((b.u >> 16) & 1u)) >> 16;
    return (rb << 16) | (ra & 0xffffu);
}

#define GLOAD16(gp, lp) __builtin_amdgcn_global_load_lds( \
    (const __attribute__((address_space(1))) void*)(gp), \
    (__attribute__((address_space(3))) void*)(lp), 16, 0, 0)

// ---------------------------------------------------------------------------
// prep: [0,436) weight transpose (4 tiles/block); [436,468) stats+MLP.
__global__ __launch_bounds__(256) void prep(
    const float* __restrict__ fusion_w, const float* __restrict__ in_proj_w,
    const float* __restrict__ out_proj_w, const float* __restrict__ ff1_w,
    const float* __restrict__ ff2_w, const float* __restrict__ cw1,
    short* __restrict__ wts,
    const int* __restrict__ s,
    short* __restrict__ semb,
    const float* __restrict__ sw1, const float* __restrict__ sb1,
    const float* __restrict__ sw2, const float* __restrict__ sb2)
{
    __shared__ float tile[4][32][33];
    __shared__ float sv_sh[512];
    __shared__ float m_sh[512];
    __shared__ float sw2_sh[2048];

    if (blockIdx.x < 436) {
        const int b0[10]      = {0,128,320,512,576,640,896,1152,1408,1664};
        const int Ks[10]      = {512,256,256,256,256,256,256,1024,1024,320};
        const int Ns[10]      = {256,768,768,256,256,1024,1024,256,256,256};
        const int sidx[10]    = {0,1,1,2,2,3,3,4,4,5};
        const size_t soff[10] = {0,0,196608,0,65536,0,262144,0,262144,0};
        const size_t doff[10] = {0,131072,327680,524288,589824,655360,917504,1179648,1441792,1703936};
        const float* srcs[6] = {fusion_w, in_proj_w, out_proj_w, ff1_w, ff2_w, cw1};
        const int c = threadIdx.x & 31, r = threadIdx.x >> 5;

        int mis[4], txs[4], tys[4];
#pragma unroll
        for (int i = 0; i < 4; ++i) {
            int tg = blockIdx.x * 4 + i;
            int mi = 0;
            while (mi < 9 && tg >= b0[mi + 1]) ++mi;
            int bl = tg - b0[mi];
            mis[i] = mi;
            txs[i] = bl % (Ns[mi] >> 5);
            tys[i] = bl / (Ns[mi] >> 5);
        }
#pragma unroll
        for (int i = 0; i < 4; ++i) {
            const float* src = srcs[sidx[mis[i]]] + soff[mis[i]];
            const int N = Ns[mis[i]];
#pragma unroll
            for (int u = 0; u < 4; ++u)
                tile[i][r + u * 8][c] =
                    src[(size_t)(tys[i] * 32 + r + u * 8) * N + txs[i] * 32 + c];
        }
        __syncthreads();
#pragma unroll
        for (int i = 0; i < 4; ++i) {
            short* dst = wts + doff[mis[i]];
            const int K = Ks[mis[i]];
#pragma unroll
            for (int u = 0; u < 4; ++u)
                dst[(size_t)(txs[i] * 32 + r + u * 8) * K + tys[i] * 32 + c] =
                    f2bf(tile[i][c][r + u * 8]);
        }
    } else {
        const int b = blockIdx.x - 436;
        const int tt = threadIdx.x;
        for (int t = tt; t < 512; t += 256) {
            int sval = s[b * 512 + t];
            bool mk = sval >= 0;
            sv_sh[t] = mk ? (float)sval : 0.f;
            m_sh[t] = mk ? 1.f : 0.f;
        }
        for (int i = tt; i < 2048; i += 256) sw2_sh[i] = sw2[i];
        __syncthreads();
        for (int half = 0; half < 2; ++half) {
            const int t = tt + half * 256;
            float mf10 = 0, sf10 = 0, mf5 = 0, sf5 = 0, d9 = 0;
#pragma unroll
            for (int k = 0; k < 10; ++k) {
                int idx = t - k;
                if (idx >= 0) {
                    float mv = m_sh[idx], sv = sv_sh[idx];
                    mf10 += mv; sf10 += sv;
                    if (k < 5) { mf5 += mv; sf5 += sv; }
                    if (k < 9 && idx >= 1) {
                        if (sv != sv_sh[idx - 1] && mv > 0.5f && m_sh[idx - 1] > 0.5f) d9 += 1.f;
                    }
                }
            }
            float run, mx;
            {
                int x0 = t - 9;
                run = (x0 >= 0) ? m_sh[x0] : 0.f;
                mx = run;
#pragma unroll
                for (int j = 1; j < 10; ++j) {
                    int xc = t + j - 9, xp = xc - 1;
                    float sc = (xc >= 0) ? sv_sh[xc] : 0.f;
                    float sp = (xp >= 0) ? sv_sh[xp] : 0.f;
                    float mc = (xc >= 0) ? m_sh[xc] : 0.f;
                    float mp = (xp >= 0) ? m_sh[xp] : 0.f;
                    bool eq = (sc == sp) && (mp > 0.5f);
                    run = (mc > 0.5f) ? ((eq ? run : 0.f) + 1.f) : 0.f;
                    mx = fmaxf(mx, run);
                }
            }
            float f[6];
            f[0] = sf10 / (mf10 + 1e-6f);
            f[1] = sf5 / (mf5 + 1e-6f);
            f[2] = d9 / (mf10 + 1e-6f);
            f[3] = mx * 0.1f;
            f[4] = (float)t * (1.f / 512.f);
            f[5] = mf10 * 0.1f;

            float hid[32];
#pragma unroll
            for (int j2 = 0; j2 < 32; ++j2) {
                float a = sb1[j2];
#pragma unroll
                for (int i = 0; i < 6; ++i) a = fmaf(f[i], sw1[i * 32 + j2], a);
                hid[j2] = fmaxf(a, 0.f);
            }
            short* orow = semb + ((size_t)b * 512 + t) * 64;
            for (int c = 0; c < 64; c += 4) {
                float v0 = sb2[c], v1 = sb2[c + 1], v2 = sb2[c + 2], v3 = sb2[c + 3];
#pragma unroll
                for (int j2 = 0; j2 < 32; ++j2) {
                    float hh = hid[j2];
                    v0 = fmaf(hh, sw2_sh[j2 * 64 + c], v0);
                    v1 = fmaf(hh, sw2_sh[j2 * 64 + c + 1], v1);
                    v2 = fmaf(hh, sw2_sh[j2 * 64 + c + 2], v2);
                    v3 = fmaf(hh, sw2_sh[j2 * 64 + c + 3], v3);
                }
                short4v o; o[0] = f2bf(v0); o[1] = f2bf(v1); o[2] = f2bf(v2); o[3] = f2bf(v3);
                *(short4v*)(orow + c) = o;
            }
        }
    }
}

// ---------------------------------------------------------------------------
// Chunked B-stationary GEMM (round-13 champion).
template<int EPI, int KTOT>
__global__ __launch_bounds__(512) void kbs(
    const short* __restrict__ A, const short* __restrict__ Wt,
    const float* __restrict__ bias,
    short* __restrict__ o0, short* __restrict__ o1, short* __restrict__ o2,
    const float* __restrict__ pos,
    const int* __restrict__ qi, const int* __restrict__ si,
    const float* __restrict__ qe, const float* __restrict__ se)
{
    constexpr int BN = 64;
    constexpr int NCH = (KTOT + 255) / 256;
    __shared__ short Bs[BN * 256];                 // 32 KB
    const int tid = threadIdx.x, lane = tid & 63, wv = tid >> 6;
    const int lg = lane >> 4, lr = lane & 15;
    const int n0 = blockIdx.y * BN;
    const int row0 = blockIdx.x * 128 + wv * 16;

    f32x4 acc[4] = {};
    short8 af[8];

#pragma unroll
    for (int c = 0; c < NCH; ++c) {
        const int ck = (KTOT - c * 256 >= 256) ? 256 : (KTOT - c * 256);
        const int spr = ck >> 3;
        if (c) __syncthreads();
        for (int i = 0; i < (BN * ck) / 8; i += 512) {
            int slot = i + tid;
            int n = slot / spr, posn = slot % spr;
            int g = posn ^ (n & 7);
            GLOAD16(Wt + (size_t)(n0 + n) * KTOT + c * 256 + g * 8, &Bs[slot * 8]);
        }
        const int nkk = ck >> 5;
        if constexpr (EPI == 0) {
            int row = row0 + lr;
            int sv = si[row];
            bool mk = sv >= 0;
            const float* base = (c == 0) ? qe + (size_t)(mk ? qi[row] : 0) * 256
                                         : se + (size_t)(mk ? sv : 0) * 256;
#pragma unroll
            for (int kk = 0; kk < 8; ++kk) {
                const float* p = base + kk * 32 + lg * 8;
                float4 v0 = *(const float4*)p;
                float4 v1 = *(const float4*)(p + 4);
                short8 o;
                o[0] = f2bf(v0.x); o[1] = f2bf(v0.y); o[2] = f2bf(v0.z); o[3] = f2bf(v0.w);
                o[4] = f2bf(v1.x); o[5] = f2bf(v1.y); o[6] = f2bf(v1.z); o[7] = f2bf(v1.w);
                af[kk] = o;
            }
        } else {
            const short* ar = A + (size_t)(row0 + lr) * KTOT + c * 256 + lg * 8;
#pragma unroll
            for (int kk = 0; kk < 8; ++kk)
                if (kk < nkk) af[kk] = *(const short8*)(ar + kk * 32);
        }
        __syncthreads();
#pragma unroll
        for (int kk = 0; kk < 8; ++kk) {
            if (kk >= nkk) break;
#pragma unroll
            for (int j = 0; j < 4; ++j) {
                int n = j * 16 + lr;
                short8 b = *(const short8*)&Bs[n * ck + (((kk * 4 + lg) ^ (n & 7)) << 3)];
                acc[j] = __builtin_amdgcn_mfma_f32_16x16x32_bf16(af[kk], b, acc[j], 0, 0, 0);
            }
        }
    }

    if constexpr (EPI == 0) {
#pragma unroll
        for (int j = 0; j < 4; ++j)
#pragma unroll
        for (int r = 0; r < 4; ++r) {
            int row = row0 + lg * 4 + r;
            int col = n0 + j * 16 + lr;
            float x = acc[j][r] + bias[col];
            x = fmaxf(x, 0.f) + pos[(size_t)(row & 511) * 256 + col];
            o0[(size_t)row * 256 + col] = f2bf(x);
        }
    } else if constexpr (EPI == 1) {
#pragma unroll
        for (int j = 0; j < 4; ++j)
#pragma unroll
        for (int r = 0; r < 4; ++r) {
            int row = row0 + lg * 4 + r;
            int gcol = n0 + j * 16 + lr;
            int t = row & 511, bg = row >> 9;
            int sec = gcol >> 8, cc = gcol & 255;
            int h = cc >> 5, d = cc & 31, bh = bg * 8 + h;
            short v = f2bf(acc[j][r] + bias[gcol]);
            if (sec == 0)      o0[((size_t)bh * 512 + t) * 32 + d] = v;
            else if (sec == 1) o1[((size_t)bh * 512 + t) * 32 + d] = v;
            else {
                int kl = t & 31;
                o2[(size_t)bh * 16384 + (size_t)(t >> 5) * 1024 +
                   (size_t)((kl >> 2) & 3) * 256 + d * 8 + (((kl & 3) << 1) | ((kl >> 4) & 1))] = v;
            }
        }
    } else {  // EPI 2: ff1 gelu
#pragma unroll
        for (int j = 0; j < 4; ++j)
#pragma unroll
        for (int r = 0; r < 4; ++r) {
            int row = row0 + lg * 4 + r;
            int gcol = n0 + j * 16 + lr;
            float x = acc[j][r] + bias[gcol];
            o0[(size_t)row * 1024 + gcol] = f2bf(gelu_f(x));
        }
    }
}

// ---------------------------------------------------------------------------
// Full-row B-stationary GEMM (round-13 champion): BN=256, 32 rows/block,
// K chunks of 128 in 64 KB LDS, grid 512. Fused row-wide epilogues:
// EPI 0: ln; EPI 1: clf.
template<int EPI, int KTOT>
__global__ __launch_bounds__(512) void kfull(
    const short* __restrict__ A, const short* __restrict__ A2,
    const short* __restrict__ Wt, const float* __restrict__ bias,
    short* __restrict__ hb,
    const float* __restrict__ gamma, const float* __restrict__ beta,
    const float* __restrict__ cw2v, const float* __restrict__ cb2,
    const int* __restrict__ smask, float* __restrict__ outlog)
{
    constexpr int NCH = (KTOT + 127) / 128;
    constexpr int KA = (EPI == 1) ? 256 : KTOT;
    __shared__ short Bs[256 * 128];                // 64 KB
    __shared__ float redS[32][4];
    __shared__ float redQ[32][4];
    const int tid = threadIdx.x, lane = tid & 63, wv = tid >> 6;
    const int lg = lane >> 4, lr = lane & 15;
    const int wr = wv >> 2, wc = wv & 3;
    const int row0 = blockIdx.x * 32 + wr * 16;

    f32x4 acc[4] = {};
    short8 af[4];

#pragma unroll
    for (int c = 0; c < NCH; ++c) {
        const int ck = (KTOT - c * 128 >= 128) ? 128 : (KTOT - c * 128);
        const int spr = ck >> 3;
        if (c) __syncthreads();
        for (int i = 0; i < (256 * ck) / 8; i += 512) {
            int slot = i + tid;
            int n = slot / spr, posn = slot % spr;
            int g = posn ^ (n & 7);
            GLOAD16(Wt + (size_t)n * KTOT + c * 128 + g * 8, &Bs[slot * 8]);
        }
        const int nkk = ck >> 5;
        if (EPI == 1 && c == 2) {
            const short* ar2 = A2 + (size_t)(row0 + lr) * 64 + lg * 8;
            af[0] = *(const short8*)(ar2);
            af[1] = *(const short8*)(ar2 + 32);
        } else {
            const short* ar = A + (size_t)(row0 + lr) * KA + c * 128 + lg * 8;
#pragma unroll
            for (int kk = 0; kk < 4; ++kk)
                if (kk < nkk) af[kk] = *(const short8*)(ar + kk * 32);
        }
        __syncthreads();
#pragma unroll
        for (int kk = 0; kk < 4; ++kk) {
            if (kk >= nkk) break;
#pragma unroll
            for (int j = 0; j < 4; ++j) {
                int n = wc * 64 + j * 16 + lr;
                short8 b = *(const short8*)&Bs[n * ck + (((kk * 4 + lg) ^ (n & 7)) << 3)];
                acc[j] = __builtin_amdgcn_mfma_f32_16x16x32_bf16(af[kk], b, acc[j], 0, 0, 0);
            }
        }
    }

    if constexpr (EPI == 0) {
        float ps[4] = {0.f, 0.f, 0.f, 0.f}, pq[4] = {0.f, 0.f, 0.f, 0.f};
#pragma unroll
        for (int j = 0; j < 4; ++j)
#pragma unroll
        for (int r = 0; r < 4; ++r) {
            int row = row0 + lg * 4 + r;
            int col = wc * 64 + j * 16 + lr;
            float x = acc[j][r] + bias[col] + bf2f(hb[(size_t)row * 256 + col]);
            acc[j][r] = x;
            ps[r] += x; pq[r] += x * x;
        }
#pragma unroll
        for (int off = 1; off < 16; off <<= 1)
#pragma unroll
            for (int r = 0; r < 4; ++r) {
                ps[r] += __shfl_xor(ps[r], off);
                pq[r] += __shfl_xor(pq[r], off);
            }
        if (lr == 0) {
#pragma unroll
            for (int r = 0; r < 4; ++r) {
                int rl = wr * 16 + lg * 4 + r;
                redS[rl][wc] = ps[r]; redQ[rl][wc] = pq[r];
            }
        }
        __syncthreads();
#pragma unroll
        for (int r = 0; r < 4; ++r) {
            int rl = wr * 16 + lg * 4 + r;
            int row = row0 + lg * 4 + r;
            float sm = redS[rl][0] + redS[rl][1] + redS[rl][2] + redS[rl][3];
            float sq = redQ[rl][0] + redQ[rl][1] + redQ[rl][2] + redQ[rl][3];
            float mu = sm * (1.f / 256.f);
            float var = sq * (1.f / 256.f) - mu * mu;
            float rstd = rsqrtf(var + 1e-5f);
#pragma unroll
            for (int j = 0; j < 4; ++j) {
                int col = wc * 64 + j * 16 + lr;
                float y = (acc[j][r] - mu) * rstd * gamma[col] + beta[col];
                hb[(size_t)row * 256 + col] = f2bf(y);
            }
        }
    } else {  // EPI 1: classifier
        float p[4] = {0.f, 0.f, 0.f, 0.f};
#pragma unroll
        for (int j = 0; j < 4; ++j)
#pragma unroll
        for (int r = 0; r < 4; ++r) {
            int col = wc * 64 + j * 16 + lr;
            float v = fmaxf(acc[j][r] + bias[col], 0.f);
            p[r] += v * cw2v[col];
        }
#pragma unroll
        for (int off = 1; off < 16; off <<= 1)
#pragma unroll
            for (int r = 0; r < 4; ++r) p[r] += __shfl_xor(p[r], off);
        if (lr == 0) {
#pragma unroll
            for (int r = 0; r < 4; ++r)
                redS[wr * 16 + lg * 4 + r][wc] = p[r];
        }
        __syncthreads();
        if (tid < 32) {
            int row = blockIdx.x * 32 + tid;
            float v = redS[tid][0] + redS[tid][1] + redS[tid][2] + redS[tid][3] + cb2[0];
            outlog[row] = (smask[row] >= 0) ? v : -1e9f;
        }
    }
}

// ---------------------------------------------------------------------------
// MFMA flash attention, fixed-max softmax, paired-tile interleave.
// XCD-local part mapping: bh = idx & 255, part = idx >> 8 — all 4 parts of a
// bh share (idx mod 8) => same XCD => K/V L2-resident for parts 2-4.
__global__ __launch_bounds__(256) void attn_mfma(
    const short* __restrict__ Qg, const short* __restrict__ Kg,
    const short* __restrict__ VTg, short* __restrict__ O)
{
    __shared__ unsigned Wp[4][2][16][20];
    const int bh = blockIdx.x & 255, part = blockIdx.x >> 8;
    const int b = bh >> 3, h = bh & 7;
    const int wv = threadIdx.x >> 6, lane = threadIdx.x & 63;
    const int lg = lane >> 4, lr = lane & 15;
    const int slot = part * 4 + wv;
    const short* Qbh = Qg + (size_t)bh * 16384;
    const short* Kbh = Kg + (size_t)bh * 16384;
    const short* Vbh = VTg + (size_t)bh * 16384;
    const float scale = 0.17677669529663687f;

    const int tA = slot, tB = 31 - slot;
    const int qA0 = tA << 4, qB0 = tB << 4;
    const int nA = tA >> 1, nB = tB >> 1;
    short8 qaA = *(const short8*)(Qbh + (size_t)(qA0 + lr) * 32 + lg * 8);
    short8 qaB = *(const short8*)(Qbh + (size_t)(qB0 + lr) * 32 + lg * 8);
    f32x4 oA0 = {}, oA1 = {}, oB0 = {}, oB1 = {};
    float lA[4] = {0.f, 0.f, 0.f, 0.f};
    float lB[4] = {0.f, 0.f, 0.f, 0.f};

    auto chunk = [&](int c, int q0, int nfull, const short8& qa,
                     const short8& kf0, const short8& kf1,
                     const short8& vf0, const short8& vf1,
                     f32x4& o0, f32x4& o1, float* l_, int slab) {
        int kc = c << 5;
        f32x4 s0 = {}, s1 = {};
        s0 = __builtin_amdgcn_mfma_f32_16x16x32_bf16(qa, kf0, s0, 0, 0, 0);
        s1 = __builtin_amdgcn_mfma_f32_16x16x32_bf16(qa, kf1, s1, 0, 0, 0);
        float p0[4], p1[4];
        if (c < nfull) {
#pragma unroll
            for (int r = 0; r < 4; ++r) {
                p0[r] = __expf(s0[r] * scale);
                p1[r] = __expf(s1[r] * scale);
            }
        } else {
#pragma unroll
            for (int r = 0; r < 4; ++r) {
                int qq = q0 + lg * 4 + r;
                p0[r] = (kc + lr)      > qq ? 0.f : __expf(s0[r] * scale);
                p1[r] = (kc + 16 + lr) > qq ? 0.f : __expf(s1[r] * scale);
            }
        }
#pragma unroll
        for (int r = 0; r < 4; ++r) {
            l_[r] += p0[r] + p1[r];
            Wp[wv][slab][lg * 4 + r][lr] = packbf(p0[r], p1[r]);
        }
        short8 pa = *(const short8*)&Wp[wv][slab][lr][lg * 4];
        o0 = __builtin_amdgcn_mfma_f32_16x16x32_bf16(pa, vf0, o0, 0, 0, 0);
        o1 = __builtin_amdgcn_mfma_f32_16x16x32_bf16(pa, vf1, o1, 0, 0, 0);
    };

    int c = 0;
    for (; c <= nA; ++c) {
        int kc = c << 5;
        short8 kf0 = *(const short8*)(Kbh + (size_t)(kc + lr) * 32 + lg * 8);
        short8 kf1 = *(const short8*)(Kbh + (size_t)(kc + 16 + lr) * 32 + lg * 8);
        short8 vf0 = *(const short8*)(Vbh + (size_t)c * 1024 + lg * 256 + lr * 8);
        short8 vf1 = *(const short8*)(Vbh + (size_t)c * 1024 + lg * 256 + (lr + 16) * 8);
        chunk(c, qB0, nB, qaB, kf0, kf1, vf0, vf1, oB0, oB1, lB, 1);
        chunk(c, qA0, nA, qaA, kf0, kf1, vf0, vf1, oA0, oA1, lA, 0);
    }
    for (; c <= nB; ++c) {
        int kc = c << 5;
        short8 kf0 = *(const short8*)(Kbh + (size_t)(kc + lr) * 32 + lg * 8);
        short8 kf1 = *(const short8*)(Kbh + (size_t)(kc + 16 + lr) * 32 + lg * 8);
        short8 vf0 = *(const short8*)(Vbh + (size_t)c * 1024 + lg * 256 + lr * 8);
        short8 vf1 = *(const short8*)(Vbh + (size_t)c * 1024 + lg * 256 + (lr + 16) * 8);
        chunk(c, qB0, nB, qaB, kf0, kf1, vf0, vf1, oB0, oB1, lB, 1);
    }

#pragma unroll
    for (int off = 1; off < 16; off <<= 1)
#pragma unroll
        for (int r = 0; r < 4; ++r) {
            lA[r] += __shfl_xor(lA[r], off);
            lB[r] += __shfl_xor(lB[r], off);
        }
#pragma unroll
    for (int r = 0; r < 4; ++r) {
        float invA = 1.f / lA[r];
        size_t roA = ((size_t)b * 512 + qA0 + lg * 4 + r) * 256 + h * 32;
        O[roA + lr] = f2bf(oA0[r] * invA);
        O[roA + 16 + lr] = f2bf(oA1[r] * invA);
        float invB = 1.f / lB[r];
        size_t roB = ((size_t)b * 512 + qB0 + lg * 4 + r) * 256 + h * 32;
        O[roB + lr] = f2bf(oB0[r] * invB);
        O[roB + 16 + lr] = f2bf(oB1[r] * invB);
    }
}

// ---------------------------------------------------------------------------
extern "C" void kernel_launch(void* const* d_in, const int* in_sizes, int n_in,
                              void* d_out, int out_size, void* d_ws, size_t ws_size,
                              hipStream_t stream) {
    const int*   q         = (const int*)d_in[0];
    const int*   s         = (const int*)d_in[1];
    const float* q_embed   = (const float*)d_in[2];
    const float* s_embed   = (const float*)d_in[3];
    const float* pos_embed = (const float*)d_in[4];
    const float* fusion_w  = (const float*)d_in[5];
    const float* fusion_b  = (const float*)d_in[6];
    const float* in_proj_w = (const float*)d_in[7];
    const float* in_proj_b = (const float*)d_in[8];
    const float* out_proj_w= (const float*)d_in[9];
    const float* out_proj_b= (const float*)d_in[10];
    const float* ln1_g     = (const float*)d_in[11];
    const float* ln1_b     = (const float*)d_in[12];
    const float* ln2_g     = (const float*)d_in[13];
    const float* ln2_b     = (const float*)d_in[14];
    const float* ff1_w     = (const float*)d_in[15];
    const float* ff1_b     = (const float*)d_in[16];
    const float* ff2_w     = (const float*)d_in[17];
    const float* ff2_b     = (const float*)d_in[18];
    const float* sw1       = (const float*)d_in[19];
    const float* sb1       = (const float*)d_in[20];
    const float* sw2       = (const float*)d_in[21];
    const float* sb2       = (const float*)d_in[22];
    const float* cw1       = (const float*)d_in[23];
    const float* cb1       = (const float*)d_in[24];
    const float* cw2       = (const float*)d_in[25];
    const float* cb2       = (const float*)d_in[26];
    float* out = (float*)d_out;

    char* base = (char*)d_ws;
    short* hb   = (short*)(base);                     // 8.39 MB
    short* bufA = (short*)(base + 8388608);           // 33.55 MB (ff mid)
    short* att  = (short*)(base + 41943040);          // 8.39 MB
    short* Qg   = (short*)(base + 50331648);          // 8.39 MB
    short* Kg   = (short*)(base + 58720256);          // 8.39 MB
    short* VTg  = (short*)(base + 67108864);          // 8.39 MB
    short* semb = (short*)(base + 75497472);          // 2.10 MB
    short* wts  = (short*)(base + 77594624);          // 3.57 MB

    const size_t W_FUSION = 0, W_INPROJ0 = 131072, W_INPROJ1 = 327680;
    const size_t W_OUTPROJ0 = 524288, W_OUTPROJ1 = 589824;
    const size_t W_FF1_0 = 655360, W_FF1_1 = 917504;
    const size_t W_FF2_0 = 1179648, W_FF2_1 = 1441792;
    const size_t W_CW1 = 1703936;

    prep<<<468, 256, 0, stream>>>(fusion_w, in_proj_w, out_proj_w,
                                  ff1_w, ff2_w, cw1, wts,
                                  s, semb, sw1, sb1, sw2, sb2);
    kbs<0, 512><<<dim3(128, 4), 512, 0, stream>>>(nullptr,
        wts + W_FUSION, fusion_b, hb, nullptr, nullptr,
        pos_embed, q, s, q_embed, s_embed);
    for (int l = 0; l < 2; ++l) {
        kbs<1, 256><<<dim3(128, 12), 512, 0, stream>>>(hb,
            wts + (l ? W_INPROJ1 : W_INPROJ0), in_proj_b + l * 768,
            Qg, Kg, VTg, nullptr, nullptr, nullptr, nullptr, nullptr);
        attn_mfma<<<1024, 256, 0, stream>>>(Qg, Kg, VTg, att);
        kfull<0, 256><<<512, 512, 0, stream>>>(att, nullptr,
            wts + (l ? W_OUTPROJ1 : W_OUTPROJ0), out_proj_b + l * 256,
            hb, ln1_g + l * 256, ln1_b + l * 256,
            nullptr, nullptr, nullptr, nullptr);
        kbs<2, 256><<<dim3(128, 16), 512, 0, stream>>>(hb,
            wts + (l ? W_FF1_1 : W_FF1_0), ff1_b + l * 1024,
            bufA, nullptr, nullptr, nullptr, nullptr, nullptr, nullptr, nullptr);
        kfull<0, 1024><<<512, 512, 0, stream>>>(bufA, nullptr,
            wts + (l ? W_FF2_1 : W_FF2_0), ff2_b + l * 256,
            hb, ln2_g + l * 256, ln2_b + l * 256,
            nullptr, nullptr, nullptr, nullptr);
    }
    kfull<1, 320><<<512, 512, 0, stream>>>(hb, semb,
        wts + W_CW1, cb1, nullptr, nullptr, nullptr,
        cw2, cb2, s, out);
}